// Round 17
// baseline (216.264 us; speedup 1.0000x reference)
//
#include <hip/hip_runtime.h>
#include <hip/hip_bf16.h>

using bf16 = __hip_bfloat16;
using bf16x8 = __attribute__((ext_vector_type(8))) short;  // 8 bf16 (4 VGPRs)
using f32x4  = __attribute__((ext_vector_type(4))) float;

#define NN 512
#define NS 511

// ---------------- workspace layout (float offsets) ----------------
enum : int {
  WS_FLAG = 0,        // int: 0 = bf16 inputs, 1 = f32 inputs (written by k_l0 blk 0)
  WS_POS2 = 1872,     // [512][3] positions after layer-0 update (layer 1 reads)
  WS_DELTA= 3408,     // [512][3] layer-0 displacement
  WS_XS1  = 4960,     // [512][64][4] (x0,x1x,x1y,x1z) for layer 1 — 16B aligned
};                     // end = 136032 floats ~= 544 KB

// exact RNE float->bf16 bits (no NaN inputs here)
__device__ __forceinline__ short f2b(float x) {
  unsigned u = __builtin_bit_cast(unsigned, x);
  unsigned r = (u + 0x7fffu + ((u >> 16) & 1u)) >> 16;
  return (short)r;
}

// dtype-branched scalar load (branch, NOT select: f32-view OOB if input is bf16)
__device__ __forceinline__ float ld(const void* p, int i, int isf32) {
  if (isf32) return ((const float*)p)[i];
  return __bfloat162float(((const bf16*)p)[i]);
}

// ---------------- layer 0: species-factorized edge + aggregate + node ----------------
// A_c[f] = sum_sp X0S[sp,f] * sum_h W2[h,f,k_c] * G[sp,c,h],
// G[sp,c,h] = sum_{s in sp} he[s,h]*Y_c[s]. r17 changes vs r16 (which was
// 70us: VALUBusy 35%, unroll-1 sender loop exposed ~120cy LDS chains at
// 2 waves/SIMD, LDS 63KB capped 2 blocks/CU):
//  (1) #pragma unroll 4 on the sender loop (iterations independent -> ILP
//      covers LDS latency),
//  (2) per-wave Gred[4][45][32] (23KB) -> single Gs + LDS atomicAdd
//      (ds_add_f32), LDS ~46KB -> 3 blocks/CU = 3 waves/SIMD.
__global__ __launch_bounds__(256) void k_l0(
    const void* __restrict__ positions, const int* __restrict__ nodef,
    const void* __restrict__ te, const void* __restrict__ W_embed,
    const void* __restrict__ b_embed, const void* __restrict__ W_lin,
    const void* __restrict__ W_e1, const void* __restrict__ b_e1,
    const void* __restrict__ W_e2, const void* __restrict__ Wp0,
    const void* __restrict__ Wp1, const void* __restrict__ Wr1,
    const void* __restrict__ br1, const void* __restrict__ Wr2g,
    float* __restrict__ ws) {
  const int j = blockIdx.x;
  const int t = threadIdx.x;
  const int lane = t & 63;
  const int wave = t >> 6;      // 0..3
  const int h = lane & 31;      // W_e1 channel
  const int half = lane >> 5;   // sender slot within wave

  __shared__ int   flag_s;
  __shared__ float posl[NN * 3];     // 6 KB
  __shared__ int   spl[NN];          // 2 KB
  __shared__ float we1s[32], be1s[32];
  __shared__ float tv[64];
  __shared__ float hstl[5][64];
  __shared__ float X0Sl[5][64];
  __shared__ float W2T[3][32][64];   // [k][h][f] fp32 — 24 KB
  __shared__ float Gs[45 * 32];      // 5.76 KB (atomicAdd target)
  __shared__ float Af[64][9];
  __shared__ float s0l[64];
  __shared__ float o1l[3][64];
  __shared__ float hl[64];

  // ---- dtype detect (wave 0), broadcast; block 0 publishes for L1 ----
  if (t < 64) {
    int cnt = 0;
    #pragma unroll
    for (int kq = 0; kq < 4; ++kq) {
      float v = __bfloat162float(((const bf16*)W_embed)[t + kq * 64]);
      float av = fabsf(v);
      cnt += (v == v && av > 1e-8f && av < 1e4f) ? 1 : 0;
    }
    #pragma unroll
    for (int off = 32; off > 0; off >>= 1) cnt += __shfl_down(cnt, off);
    if (t == 0) {
      int f32v = (cnt >= 240) ? 0 : 1;
      flag_s = f32v;
      if (j == 0) ((int*)ws)[WS_FLAG] = f32v;
    }
  }
  __syncthreads();
  const int isf32 = flag_s;

  // ---- stage pos, species, W_e1/b_e1, W2 (fp32, [k][h][f]); zero Gs ----
  for (int idx = t; idx < NN * 3; idx += 256) posl[idx] = ld(positions, idx, isf32);
  for (int idx = t; idx < NN; idx += 256) spl[idx] = nodef[idx] - 1;
  if (t < 32)      we1s[t]      = ld(W_e1, t, isf32);       // layer 0
  else if (t < 64) be1s[t - 32] = ld(b_e1, t - 32, isf32);
  for (int idx = t; idx < 3 * 32 * 64; idx += 256) {
    int k = idx >> 11, rem = idx & 2047;
    int hh = rem >> 6, f = rem & 63;
    W2T[k][hh][f] = ld(W_e2, hh * 384 + f * 6 + k, isf32);  // layer 0 slice
  }
  for (int idx = t; idx < 45 * 32; idx += 256) Gs[idx] = 0.f;
  // ---- embedding collapse: tv, hst, X0S (per-block, cheap) ----
  if (t < 64) {
    float s = ld(b_embed, t, isf32);
    #pragma unroll 8
    for (int q = 0; q < 32; ++q)
      s += ld(te, q, isf32) * ld(W_embed, (5 + q) * 64 + t, isf32);
    tv[t] = s;
  }
  __syncthreads();
  for (int o = t; o < 320; o += 256) {
    int sp = o >> 6, q = o & 63;
    hstl[sp][q] = tv[q] + ld(W_embed, sp * 64 + q, isf32);
  }
  __syncthreads();
  for (int o = t; o < 320; o += 256) {
    int sp = o >> 6, f = o & 63;
    float a0 = 0.f;
    #pragma unroll 8
    for (int q = 0; q < 64; ++q)
      a0 += hstl[sp][q] * ld(W_lin, q * 64 + f, isf32);
    X0Sl[sp][f] = a0;
  }
  __syncthreads();

  const float s3 = 1.7320508075688772f;
  const float s5h = 1.118033988749895f;    // 0.5*sqrt(5)
  const float s15 = 3.872983346207417f;
  const float s15h = 1.9364916731037085f;  // 0.5*sqrt(15)

  const float pjx = posl[j * 3 + 0], pjy = posl[j * 3 + 1], pjz = posl[j * 3 + 2];
  const float we1h = we1s[h], be1h = be1s[h];

  // ---- sender loop: accumulate G[sp*9+c] for my h (unroll 4 for ILP) ----
  float G[45];
  #pragma unroll
  for (int c = 0; c < 45; ++c) G[c] = 0.f;

  #pragma unroll 4
  for (int it = 0; it < 64; ++it) {
    int sidx = it * 8 + wave * 2 + half;
    if (sidx < NS) {
      int i = sidx + (sidx >= j);
      float pix = posl[i * 3 + 0], piy = posl[i * 3 + 1], piz = posl[i * 3 + 2];
      float vx = pjx - pix, vy = pjy - piy, vz = pjz - piz;
      float r2 = vx * vx + vy * vy + vz * vz;
      float rinv = r2 > 0.f ? rsqrtf(r2) : 0.f;
      float r = r2 * rinv;  // sqrt(r2)
      float ux = vx * rinv, uy = vy * rinv, uz = vz * rinv;
      float x = r * we1h + be1h;
      float he = x / (1.f + __expf(-x));  // silu
      float Y1x = s3 * ux, Y1y = s3 * uy, Y1z = s3 * uz;
      float Y2a = s15 * ux * uy, Y2b = s15 * uy * uz;
      float Y2c = s5h * (3.f * uz * uz - 1.f);
      float Y2d = s15 * ux * uz, Y2e = s15h * (ux * ux - uy * uy);
      int sp = spl[i];
      #pragma unroll
      for (int spi = 0; spi < 5; ++spi) {
        float hem = (sp == spi) ? he : 0.f;
        G[spi * 9 + 0] += hem;
        G[spi * 9 + 1] += hem * Y1x;
        G[spi * 9 + 2] += hem * Y1y;
        G[spi * 9 + 3] += hem * Y1z;
        G[spi * 9 + 4] += hem * Y2a;
        G[spi * 9 + 5] += hem * Y2b;
        G[spi * 9 + 6] += hem * Y2c;
        G[spi * 9 + 7] += hem * Y2d;
        G[spi * 9 + 8] += hem * Y2e;
      }
    }
  }

  // ---- reduce: halves (lane^32 shares h), then atomics into Gs ----
  #pragma unroll
  for (int c = 0; c < 45; ++c) G[c] += __shfl_xor(G[c], 32);
  if (lane < 32) {
    #pragma unroll
    for (int c = 0; c < 45; ++c) atomicAdd(&Gs[c * 32 + h], G[c]);
  }
  __syncthreads();

  // ---- A_c[f] = sum_sp X0S[sp,f] * (G[sp,c,:] . W2T[k_c][:,f]) ----
  for (int o = t; o < 576; o += 256) {
    int f = o & 63, c = o >> 6;   // lanes sweep f: W2T 2-way bank (free)
    int kc = (c == 0) ? 0 : (c < 4 ? 1 : 2);
    float s = 0.f;
    #pragma unroll
    for (int sp = 0; sp < 5; ++sp) {
      float d = 0.f;
      #pragma unroll 8
      for (int hh = 0; hh < 32; ++hh)
        d += Gs[(sp * 9 + c) * 32 + hh] * W2T[kc][hh][f];
      s += X0Sl[sp][f] * d;
    }
    Af[f][c] = s * (1.f / 511.f);
  }
  __syncthreads();

  // ---- node-update tail (wave 0) ----
  float out0 = 0.f, o1x = 0.f, o1y = 0.f, o1z = 0.f;
  if (t < 64) {
    int f = t;
    float a[9];
    #pragma unroll
    for (int c = 0; c < 9; ++c) a[c] = Af[f][c];
    int sp = nodef[j] - 1;
    int b0i = (sp * 64 + f) * 6;
    int b1i = (sp * 64 + f) * 3;
    float A0 = a[0];
    float n1 = a[1] * a[1] + a[2] * a[2] + a[3] * a[3];
    float n2 = a[4] * a[4] + a[5] * a[5] + a[6] * a[6] + a[7] * a[7] + a[8] * a[8];
    float A02 = A0 * A0;
    out0 = ld(Wp0, b0i + 0, isf32) * A0 + ld(Wp0, b0i + 1, isf32) * A02 +
           ld(Wp0, b0i + 2, isf32) * A02 * A0 + ld(Wp0, b0i + 3, isf32) * n1 +
           ld(Wp0, b0i + 4, isf32) * n2 + ld(Wp0, b0i + 5, isf32) * A0 * n1;
    float gp = ld(Wp1, b1i + 0, isf32) + ld(Wp1, b1i + 1, isf32) * A0 +
               ld(Wp1, b1i + 2, isf32) * A02;
    o1x = gp * a[1]; o1y = gp * a[2]; o1z = gp * a[3];
    s0l[f] = out0;
    o1l[0][f] = o1x; o1l[1][f] = o1y; o1l[2][f] = o1z;
  }
  __syncthreads();
  if (t < 64) {
    int f = t;
    // layer-1 node linear into XS1
    float b0 = 0.f, bx = 0.f, by = 0.f, bz = 0.f;
    #pragma unroll 8
    for (int q = 0; q < 64; ++q) {
      float w0 = ld(W_lin, 3 * 4096 + q * 64 + f, isf32);  // layer1, path0
      float w1 = ld(W_lin, 4 * 4096 + q * 64 + f, isf32);  // layer1, path1
      b0 += s0l[q] * w0;
      bx += o1l[0][q] * w1; by += o1l[1][q] * w1; bz += o1l[2][q] * w1;
    }
    f32x4 o = {b0, bx, by, bz};
    *(f32x4*)&ws[WS_XS1 + (j * 64 + f) * 4] = o;
    float hacc = ld(br1, f, isf32);
    #pragma unroll 8
    for (int q = 0; q < 64; ++q)
      hacc += s0l[q] * ld(Wr1, q * 64 + f, isf32);
    hl[f] = hacc / (1.f + __expf(-hacc));
  }
  __syncthreads();
  if (t < 64) {
    int f = t;
    float gacc = 0.f;
    #pragma unroll 8
    for (int m = 0; m < 64; ++m)
      gacc += hl[m] * ld(Wr2g, m * 64 + f, isf32);
    float px = gacc * o1x, py = gacc * o1y, pz = gacc * o1z;
    #pragma unroll
    for (int off = 32; off > 0; off >>= 1) {
      px += __shfl_down(px, off);
      py += __shfl_down(py, off);
      pz += __shfl_down(pz, off);
    }
    if (f == 0) {
      ws[WS_DELTA + j * 3 + 0] = px;
      ws[WS_DELTA + j * 3 + 1] = py;
      ws[WS_DELTA + j * 3 + 2] = pz;
      ws[WS_POS2 + j * 3 + 0] = pjx + px;
      ws[WS_POS2 + j * 3 + 1] = pjy + py;
      ws[WS_POS2 + j * 3 + 2] = pjz + pz;
    }
  }
}

// ---------------- layer 1: fused edge + aggregate + node (r14 verbatim) ----------------
// CAPLESS __launch_bounds__ (min-waves bound -> 50/50 arch/AGPR split ->
// ~1KB/thread HBM spill, r4-r8/r11). Body is the proven local optimum.
__global__ __launch_bounds__(256) void k_edgenode1(
    const int* __restrict__ nodef, const void* __restrict__ W_lin,
    const void* __restrict__ W_e1, const void* __restrict__ b_e1,
    const void* __restrict__ W_e2, const void* __restrict__ Wp0,
    const void* __restrict__ Wp1, const void* __restrict__ Wr1,
    const void* __restrict__ br1, const void* __restrict__ Wr2g,
    float* __restrict__ ws, void* __restrict__ out) {
  constexpr int L = 1;
  constexpr int K = 5;
  constexpr int N = K * 64;
  const int j = blockIdx.x;
  const int t = threadIdx.x;
  const int lane = t & 63;
  const int wave = t >> 6;
  const int quad = lane >> 4;
  const int lo = lane & 15;

  __shared__ short Bhi[N * 40];
  __shared__ float red[4][64][9];
  __shared__ float Af[64][9];
  __shared__ float s0l[64];
  __shared__ float hl[64];

  const int isf32 = ((const int*)ws)[WS_FLAG];

  {
    for (int idx = t; idx < N * 32; idx += 256) {
      int n = idx >> 5, hh = idx & 31;
      int kp = n >> 6, f = n & 63;
      int src = (L * 32 + hh) * 384 + f * 6 + kp;
      short bits;
      if (isf32) bits = f2b(((const float*)W_e2)[src]);
      else       bits = ((const short*)W_e2)[src];
      Bhi[n * 40 + hh] = bits;
    }
  }
  const float* pos = ws + WS_POS2;
  const f32x4* xs = (const f32x4*)(ws + WS_XS1);
  float we1v[8], be1v[8];
  #pragma unroll
  for (int i = 0; i < 8; ++i) {
    we1v[i] = ld(W_e1, L * 32 + quad * 8 + i, isf32);
    be1v[i] = ld(b_e1, L * 32 + quad * 8 + i, isf32);
  }
  const float pjx = pos[j * 3 + 0], pjy = pos[j * 3 + 1], pjz = pos[j * 3 + 2];

  const float s3 = 1.7320508075688772f;
  const float s5h = 1.118033988749895f;
  const float s15 = 3.872983346207417f;
  const float s15h = 1.9364916731037085f;

  float acc[9][4] = {};
  __syncthreads();

  #pragma unroll 1
  for (int stile = wave; stile < 32; stile += 4) {
    bf16x8 af;
    {
      int ida = stile * 16 + lo;
      int ia = ida + (ida >= j);
      if (ia > 511) ia = 511;
      float pix = pos[ia * 3 + 0], piy = pos[ia * 3 + 1], piz = pos[ia * 3 + 2];
      float vx = pjx - pix, vy = pjy - piy, vz = pjz - piz;
      float r = sqrtf(vx * vx + vy * vy + vz * vz);
      #pragma unroll
      for (int i = 0; i < 8; ++i) {
        float x = r * we1v[i] + be1v[i];
        float he = x / (1.f + __expf(-x));
        af[i] = f2b(he);
      }
    }
    float Y1r[4][3], Y2r[4][5];
    int ir[4];
    bool vld[4];
    #pragma unroll
    for (int r4 = 0; r4 < 4; ++r4) {
      int idx = stile * 16 + quad * 4 + r4;
      vld[r4] = idx < NS;
      int i = idx + (idx >= j);
      if (i > 511) i = 511;
      ir[r4] = i;
      float pix = pos[i * 3 + 0], piy = pos[i * 3 + 1], piz = pos[i * 3 + 2];
      float vx = pjx - pix, vy = pjy - piy, vz = pjz - piz;
      float r2 = vx * vx + vy * vy + vz * vz;
      float rinv = r2 > 0.f ? rsqrtf(r2) : 0.f;
      float ux = vx * rinv, uy = vy * rinv, uz = vz * rinv;
      Y1r[r4][0] = s3 * ux; Y1r[r4][1] = s3 * uy; Y1r[r4][2] = s3 * uz;
      Y2r[r4][0] = s15 * ux * uy;
      Y2r[r4][1] = s15 * uy * uz;
      Y2r[r4][2] = s5h * (3.f * uz * uz - 1.f);
      Y2r[r4][3] = s15 * ux * uz;
      Y2r[r4][4] = s15h * (ux * ux - uy * uy);
    }
    #pragma unroll
    for (int ft = 0; ft < 4; ++ft) {
      int fcol = ft * 16 + lo;
      f32x4 xv[4];
      #pragma unroll
      for (int r4 = 0; r4 < 4; ++r4) xv[r4] = xs[ir[r4] * 64 + fcol];
      f32x4 C[K];
      #pragma unroll
      for (int kp = 0; kp < K; ++kp) {
        const bf16x8 bh = *(const bf16x8*)&Bhi[(kp * 64 + fcol) * 40 + quad * 8];
        f32x4 c = {0.f, 0.f, 0.f, 0.f};
        C[kp] = __builtin_amdgcn_mfma_f32_16x16x32_bf16(af, bh, c, 0, 0, 0);
      }
      #pragma unroll
      for (int r4 = 0; r4 < 4; ++r4) {
        if (vld[r4]) {
          float s0 = xv[r4].x;
          float w0 = C[0][r4], w1 = C[1][r4], w2 = C[2][r4];
          float s1x = xv[r4].y, s1y = xv[r4].z, s1z = xv[r4].w;
          float w3 = C[3][r4], w4 = C[4][r4];
          float d1 = s1x * Y1r[r4][0] + s1y * Y1r[r4][1] + s1z * Y1r[r4][2];
          float cx = s1y * Y1r[r4][2] - s1z * Y1r[r4][1];
          float cy = s1z * Y1r[r4][0] - s1x * Y1r[r4][2];
          float cz = s1x * Y1r[r4][1] - s1y * Y1r[r4][0];
          acc[0][ft] += w0 * s0 + w3 * d1;
          float t1 = w1 * s0;
          acc[1][ft] += t1 * Y1r[r4][0] + w4 * cx;
          acc[2][ft] += t1 * Y1r[r4][1] + w4 * cy;
          acc[3][ft] += t1 * Y1r[r4][2] + w4 * cz;
          float t2 = w2 * s0;
          acc[4][ft] += t2 * Y2r[r4][0];
          acc[5][ft] += t2 * Y2r[r4][1];
          acc[6][ft] += t2 * Y2r[r4][2];
          acc[7][ft] += t2 * Y2r[r4][3];
          acc[8][ft] += t2 * Y2r[r4][4];
        }
      }
    }
  }

  #pragma unroll
  for (int c = 0; c < 9; ++c)
    #pragma unroll
    for (int ft = 0; ft < 4; ++ft) {
      float v = acc[c][ft];
      v += __shfl_xor(v, 16);
      v += __shfl_xor(v, 32);
      acc[c][ft] = v;
    }
  if (quad == 0) {
    #pragma unroll
    for (int c = 0; c < 9; ++c)
      #pragma unroll
      for (int ft = 0; ft < 4; ++ft)
        red[wave][ft * 16 + lo][c] = acc[c][ft];
  }
  __syncthreads();
  for (int o = t; o < 576; o += 256) {
    int f = o / 9, c = o % 9;
    Af[f][c] = (red[0][f][c] + red[1][f][c] + red[2][f][c] + red[3][f][c]) *
               (1.f / 511.f);
  }
  __syncthreads();

  float out0 = 0.f, o1x = 0.f, o1y = 0.f, o1z = 0.f;
  if (t < 64) {
    int f = t;
    float a[9];
    #pragma unroll
    for (int c = 0; c < 9; ++c) a[c] = Af[f][c];
    int sp = nodef[j] - 1;
    int b0i = ((L * 5 + sp) * 64 + f) * 6;
    int b1i = ((L * 5 + sp) * 64 + f) * 3;
    float A0 = a[0];
    float n1 = a[1] * a[1] + a[2] * a[2] + a[3] * a[3];
    float n2 = a[4] * a[4] + a[5] * a[5] + a[6] * a[6] + a[7] * a[7] + a[8] * a[8];
    float A02 = A0 * A0;
    out0 = ld(Wp0, b0i + 0, isf32) * A0 + ld(Wp0, b0i + 1, isf32) * A02 +
           ld(Wp0, b0i + 2, isf32) * A02 * A0 + ld(Wp0, b0i + 3, isf32) * n1 +
           ld(Wp0, b0i + 4, isf32) * n2 + ld(Wp0, b0i + 5, isf32) * A0 * n1;
    float gp = ld(Wp1, b1i + 0, isf32) + ld(Wp1, b1i + 1, isf32) * A0 +
               ld(Wp1, b1i + 2, isf32) * A02;
    o1x = gp * a[1]; o1y = gp * a[2]; o1z = gp * a[3];
    s0l[f] = out0;
  }
  __syncthreads();
  if (t < 64) {
    int f = t;
    float hacc = ld(br1, L * 64 + f, isf32);
    #pragma unroll 8
    for (int q = 0; q < 64; ++q)
      hacc += s0l[q] * ld(Wr1, (L * 64 + q) * 64 + f, isf32);
    hl[f] = hacc / (1.f + __expf(-hacc));
  }
  __syncthreads();
  if (t < 64) {
    int f = t;
    float gacc = 0.f;
    #pragma unroll 8
    for (int m = 0; m < 64; ++m)
      gacc += hl[m] * ld(Wr2g, (L * 64 + m) * 64 + f, isf32);
    float px = gacc * o1x, py = gacc * o1y, pz = gacc * o1z;
    #pragma unroll
    for (int off = 32; off > 0; off >>= 1) {
      px += __shfl_down(px, off);
      py += __shfl_down(py, off);
      pz += __shfl_down(pz, off);
    }
    if (f == 0) {
      float ox = ws[WS_DELTA + j * 3 + 0] + px;
      float oy = ws[WS_DELTA + j * 3 + 1] + py;
      float oz = ws[WS_DELTA + j * 3 + 2] + pz;
      if (isf32) {
        float* o = (float*)out;
        o[j * 3 + 0] = ox; o[j * 3 + 1] = oy; o[j * 3 + 2] = oz;
      } else {
        bf16* o = (bf16*)out;
        o[j * 3 + 0] = __float2bfloat16(ox);
        o[j * 3 + 1] = __float2bfloat16(oy);
        o[j * 3 + 2] = __float2bfloat16(oz);
      }
    }
  }
}

extern "C" void kernel_launch(void* const* d_in, const int* in_sizes, int n_in,
                              void* d_out, int out_size, void* d_ws, size_t ws_size,
                              hipStream_t stream) {
  const void* positions = d_in[0];
  const int*  nodef     = (const int*)d_in[1];
  const void* te        = d_in[2];
  const void* W_embed   = d_in[5];
  const void* b_embed   = d_in[6];
  const void* W_lin     = d_in[7];
  const void* W_e1      = d_in[8];
  const void* b_e1      = d_in[9];
  const void* W_e2      = d_in[10];
  const void* Wp0       = d_in[11];
  const void* Wp1       = d_in[12];
  const void* Wr1       = d_in[13];
  const void* br1       = d_in[14];
  const void* Wr2g      = d_in[16];
  float* ws = (float*)d_ws;
  (void)in_sizes; (void)n_in; (void)out_size; (void)ws_size;

  k_l0<<<dim3(512), dim3(256), 0, stream>>>(
      positions, nodef, te, W_embed, b_embed, W_lin, W_e1, b_e1, W_e2,
      Wp0, Wp1, Wr1, br1, Wr2g, ws);
  k_edgenode1<<<dim3(512), dim3(256), 0, stream>>>(
      nodef, W_lin, W_e1, b_e1, W_e2, Wp0, Wp1, Wr1, br1, Wr2g, ws, d_out);
}

// Round 18
// 188.378 us; speedup vs baseline: 1.1480x; 1.1480x over previous
//
#include <hip/hip_runtime.h>
#include <hip/hip_bf16.h>

using bf16 = __hip_bfloat16;
using bf16x8 = __attribute__((ext_vector_type(8))) short;  // 8 bf16 (4 VGPRs)
using f32x4  = __attribute__((ext_vector_type(4))) float;

#define NN 512
#define NS 511

// ---------------- workspace layout (float offsets) ----------------
enum : int {
  WS_FLAG = 0,        // int: 0 = bf16 inputs, 1 = f32 inputs
  WS_X0S  = 16,       // [5][64] species-indexed layer-0 x0 rows (only 5 distinct!)
  WS_POS  = 336,      // [512][3] positions fp32 (layer 0)
  WS_POS2 = 1872,     // [512][3] positions after layer-0 update (layer 1 reads)
  WS_DELTA= 3408,     // [512][3] layer-0 displacement
  WS_XS1  = 4960,     // [512][64][4] (x0,x1x,x1y,x1z) for layer 1 — 16B aligned
};                     // end = 136032 floats ~= 544 KB

// exact RNE float->bf16 bits (no NaN inputs here)
__device__ __forceinline__ short f2b(float x) {
  unsigned u = __builtin_bit_cast(unsigned, x);
  unsigned r = (u + 0x7fffu + ((u >> 16) & 1u)) >> 16;
  return (short)r;
}

// dtype-branched scalar load (branch, NOT select: f32-view OOB if input is bf16)
__device__ __forceinline__ float ld(const void* p, int i, int isf32) {
  if (isf32) return ((const float*)p)[i];
  return __bfloat162float(((const bf16*)p)[i]);
}

// ---------------- pre (6 blocks): detect + pos convert + X0S ----------------
// r14's k_pre was ONE block: two serial global-latency chains (32-iter tv,
// 64-iter X0S) on one CU, sitting on the critical path before the 512-block
// edge kernel. Parallelized: blocks 0-4 compute X0S[sp] with the reduction
// split across thread chunks (all global loads lane-coalesced); block 5
// converts positions and publishes the dtype flag.
__global__ __launch_bounds__(256) void k_pre(
    const void* __restrict__ positions, const void* __restrict__ te,
    const void* __restrict__ W_embed, const void* __restrict__ b_embed,
    const void* __restrict__ W_lin, float* __restrict__ ws) {
  const int b = blockIdx.x, t = threadIdx.x;
  __shared__ int flag_s;
  __shared__ float tvp[4][64];
  __shared__ float hst[64];
  __shared__ float xp[4][64];
  // ---- dtype detect (wave 0) on W_embed's first 256 bf16-view elements ----
  if (t < 64) {
    int cnt = 0;
    #pragma unroll
    for (int kq = 0; kq < 4; ++kq) {
      float v = __bfloat162float(((const bf16*)W_embed)[t + kq * 64]);
      float av = fabsf(v);
      cnt += (v == v && av > 1e-8f && av < 1e4f) ? 1 : 0;
    }
    #pragma unroll
    for (int off = 32; off > 0; off >>= 1) cnt += __shfl_down(cnt, off);
    if (t == 0) flag_s = (cnt >= 240) ? 0 : 1;
  }
  __syncthreads();
  const int isf32 = flag_s;

  if (b == 5) {
    if (t == 0) ((int*)ws)[WS_FLAG] = isf32;
    for (int idx = t; idx < NN * 3; idx += 256)
      ws[WS_POS + idx] = ld(positions, idx, isf32);
    return;
  }
  // blocks 0..4: X0S[b][:] = (b_embed + te@W_embed[5:] + W_embed[b]) @ W0_l0
  {
    int q = t & 63, kc = t >> 6;  // 4 k-chunks of 8
    float ptv = 0.f;
    #pragma unroll
    for (int k = kc * 8; k < kc * 8 + 8; ++k)
      ptv += ld(te, k, isf32) * ld(W_embed, (5 + k) * 64 + q, isf32);
    tvp[kc][q] = ptv;
  }
  __syncthreads();
  if (t < 64)
    hst[t] = tvp[0][t] + tvp[1][t] + tvp[2][t] + tvp[3][t] +
             ld(b_embed, t, isf32) + ld(W_embed, b * 64 + t, isf32);
  __syncthreads();
  {
    int f = t & 63, qc = t >> 6;  // 4 q-chunks of 16
    float px = 0.f;
    #pragma unroll
    for (int q2 = qc * 16; q2 < qc * 16 + 16; ++q2)
      px += hst[q2] * ld(W_lin, q2 * 64 + f, isf32);  // layer0 path0
    xp[qc][f] = px;
  }
  __syncthreads();
  if (t < 64)
    ws[WS_X0S + b * 64 + t] = xp[0][t] + xp[1][t] + xp[2][t] + xp[3][t];
}

// ---------------- fused edge + aggregate + node update (r14 verbatim) ----------------
// One block per receiver j (grid 512); 256 threads (4 waves). CAPLESS
// __launch_bounds__ (min-waves bound -> 50/50 arch/AGPR split ->
// ~1KB/thread HBM spill, r4-r8/r11). Body is the proven local optimum:
// hoisting (r5/r6/r12), dieting (r11/r13), ft-split (r15), and the
// species-factorized L0 (r16/r17) all regressed. L0 sender features come
// from the 1.25KB species-indexed X0S table staged in LDS.
template <int L>
__global__ __launch_bounds__(256) void k_edgenode(
    const int* __restrict__ nodef, const void* __restrict__ W_lin,
    const void* __restrict__ W_e1, const void* __restrict__ b_e1,
    const void* __restrict__ W_e2, const void* __restrict__ Wp0,
    const void* __restrict__ Wp1, const void* __restrict__ Wr1,
    const void* __restrict__ br1, const void* __restrict__ Wr2g,
    float* __restrict__ ws, void* __restrict__ out) {
  constexpr int HAS1 = L;          // s1==0 in layer 0
  constexpr int K = HAS1 ? 5 : 3;  // s2==0 always
  constexpr int N = K * 64;
  const int j = blockIdx.x;
  const int t = threadIdx.x;
  const int lane = t & 63;
  const int wave = t >> 6;          // 0..3
  const int quad = lane >> 4;
  const int lo = lane & 15;

  __shared__ short Bhi[N * 40];     // [n][h], row stride 40 shorts (80B, 16B-aligned)
  __shared__ float red[4][64][9];
  __shared__ float Af[64][9];
  __shared__ float s0l[64];
  __shared__ float o1l[3][64];
  __shared__ float hl[64];
  __shared__ float X0l[320];        // L0: species-indexed x0 table

  const int isf32 = ((const int*)ws)[WS_FLAG];

  {  // stage W2 slice -> LDS bf16 (direct bit copy if input already bf16)
    for (int idx = t; idx < N * 32; idx += 256) {
      int n = idx >> 5, h = idx & 31;
      int kp = n >> 6, f = n & 63;
      int src = (L * 32 + h) * 384 + f * 6 + kp;
      short bits;
      if (isf32) bits = f2b(((const float*)W_e2)[src]);
      else       bits = ((const short*)W_e2)[src];
      Bhi[n * 40 + h] = bits;
    }
    if (!HAS1) {
      for (int idx = t; idx < 320; idx += 256) X0l[idx] = ws[WS_X0S + idx];
    }
  }
  const float* pos = ws + (L ? WS_POS2 : WS_POS);
  const f32x4* xs = (const f32x4*)(ws + WS_XS1);  // used only for L==1
  float we1v[8], be1v[8];
  #pragma unroll
  for (int i = 0; i < 8; ++i) {
    we1v[i] = ld(W_e1, L * 32 + quad * 8 + i, isf32);
    be1v[i] = ld(b_e1, L * 32 + quad * 8 + i, isf32);
  }
  const float pjx = pos[j * 3 + 0], pjy = pos[j * 3 + 1], pjz = pos[j * 3 + 2];

  const float s3 = 1.7320508075688772f;
  const float s5h = 1.118033988749895f;    // 0.5*sqrt(5)
  const float s15 = 3.872983346207417f;
  const float s15h = 1.9364916731037085f;  // 0.5*sqrt(15)

  float acc[9][4] = {};  // [c][ft]
  __syncthreads();

  #pragma unroll 1
  for (int stile = wave; stile < 32; stile += 4) {
    // ---- A fragment: he for sender m=lo, k=quad*8+i ----
    bf16x8 af;
    {
      int ida = stile * 16 + lo;
      int ia = ida + (ida >= j);
      if (ia > 511) ia = 511;
      float pix = pos[ia * 3 + 0], piy = pos[ia * 3 + 1], piz = pos[ia * 3 + 2];
      float vx = pjx - pix, vy = pjy - piy, vz = pjz - piz;
      float r = sqrtf(vx * vx + vy * vy + vz * vz);
      #pragma unroll
      for (int i = 0; i < 8; ++i) {
        float x = r * we1v[i] + be1v[i];
        float he = x / (1.f + __expf(-x));
        af[i] = f2b(he);
      }
    }
    // ---- Y + indices (+ species for L0) for this quad's 4 row-senders ----
    float Y1r[4][3], Y2r[4][5];
    int ir[4], sp4[4];
    bool vld[4];
    #pragma unroll
    for (int r4 = 0; r4 < 4; ++r4) {
      int idx = stile * 16 + quad * 4 + r4;
      vld[r4] = idx < NS;
      int i = idx + (idx >= j);
      if (i > 511) i = 511;
      ir[r4] = i;
      if (!HAS1) sp4[r4] = nodef[i] - 1;
      float pix = pos[i * 3 + 0], piy = pos[i * 3 + 1], piz = pos[i * 3 + 2];
      float vx = pjx - pix, vy = pjy - piy, vz = pjz - piz;
      float r2 = vx * vx + vy * vy + vz * vz;
      float rinv = r2 > 0.f ? rsqrtf(r2) : 0.f;
      float ux = vx * rinv, uy = vy * rinv, uz = vz * rinv;
      Y1r[r4][0] = s3 * ux; Y1r[r4][1] = s3 * uy; Y1r[r4][2] = s3 * uz;
      Y2r[r4][0] = s15 * ux * uy;
      Y2r[r4][1] = s15 * uy * uz;
      Y2r[r4][2] = s5h * (3.f * uz * uz - 1.f);
      Y2r[r4][3] = s15 * ux * uz;
      Y2r[r4][4] = s15h * (ux * ux - uy * uy);
    }
    // ---- per f-subtile: loads, K MFMAs, then message math ----
    #pragma unroll
    for (int ft = 0; ft < 4; ++ft) {
      int fcol = ft * 16 + lo;
      f32x4 xv[4];
      if (HAS1) {
        #pragma unroll
        for (int r4 = 0; r4 < 4; ++r4) xv[r4] = xs[ir[r4] * 64 + fcol];
      } else {
        #pragma unroll
        for (int r4 = 0; r4 < 4; ++r4) {
          f32x4 v = {X0l[sp4[r4] * 64 + fcol], 0.f, 0.f, 0.f};
          xv[r4] = v;
        }
      }
      f32x4 C[K];
      #pragma unroll
      for (int kp = 0; kp < K; ++kp) {
        const bf16x8 bh = *(const bf16x8*)&Bhi[(kp * 64 + fcol) * 40 + quad * 8];
        f32x4 c = {0.f, 0.f, 0.f, 0.f};
        C[kp] = __builtin_amdgcn_mfma_f32_16x16x32_bf16(af, bh, c, 0, 0, 0);
      }
      #pragma unroll
      for (int r4 = 0; r4 < 4; ++r4) {
        if (vld[r4]) {
          float s0 = xv[r4].x;
          float w0 = C[0][r4], w1 = C[1][r4], w2 = C[2][r4];
          if (HAS1) {
            float s1x = xv[r4].y, s1y = xv[r4].z, s1z = xv[r4].w;
            float w3 = C[3][r4], w4 = C[4][r4];
            float d1 = s1x * Y1r[r4][0] + s1y * Y1r[r4][1] + s1z * Y1r[r4][2];
            float cx = s1y * Y1r[r4][2] - s1z * Y1r[r4][1];
            float cy = s1z * Y1r[r4][0] - s1x * Y1r[r4][2];
            float cz = s1x * Y1r[r4][1] - s1y * Y1r[r4][0];
            acc[0][ft] += w0 * s0 + w3 * d1;
            float t1 = w1 * s0;
            acc[1][ft] += t1 * Y1r[r4][0] + w4 * cx;
            acc[2][ft] += t1 * Y1r[r4][1] + w4 * cy;
            acc[3][ft] += t1 * Y1r[r4][2] + w4 * cz;
          } else {
            acc[0][ft] += w0 * s0;
            float t1 = w1 * s0;
            acc[1][ft] += t1 * Y1r[r4][0];
            acc[2][ft] += t1 * Y1r[r4][1];
            acc[3][ft] += t1 * Y1r[r4][2];
          }
          float t2 = w2 * s0;
          acc[4][ft] += t2 * Y2r[r4][0];
          acc[5][ft] += t2 * Y2r[r4][1];
          acc[6][ft] += t2 * Y2r[r4][2];
          acc[7][ft] += t2 * Y2r[r4][3];
          acc[8][ft] += t2 * Y2r[r4][4];
        }
      }
    }
  }

  // ---- reduce over quads (butterfly), then over 4 waves (LDS) -> Af ----
  #pragma unroll
  for (int c = 0; c < 9; ++c)
    #pragma unroll
    for (int ft = 0; ft < 4; ++ft) {
      float v = acc[c][ft];
      v += __shfl_xor(v, 16);
      v += __shfl_xor(v, 32);
      acc[c][ft] = v;
    }
  if (quad == 0) {
    #pragma unroll
    for (int c = 0; c < 9; ++c)
      #pragma unroll
      for (int ft = 0; ft < 4; ++ft)
        red[wave][ft * 16 + lo][c] = acc[c][ft];
  }
  __syncthreads();
  for (int o = t; o < 576; o += 256) {
    int f = o / 9, c = o % 9;
    Af[f][c] = (red[0][f][c] + red[1][f][c] + red[2][f][c] + red[3][f][c]) *
               (1.f / 511.f);
  }
  __syncthreads();

  // ---- node-update tail (wave 0; other waves ride the barriers) ----
  float out0 = 0.f, o1x = 0.f, o1y = 0.f, o1z = 0.f;
  if (t < 64) {
    int f = t;
    float a[9];
    #pragma unroll
    for (int c = 0; c < 9; ++c) a[c] = Af[f][c];
    int sp = nodef[j] - 1;
    int b0i = ((L * 5 + sp) * 64 + f) * 6;
    int b1i = ((L * 5 + sp) * 64 + f) * 3;
    float A0 = a[0];
    float n1 = a[1] * a[1] + a[2] * a[2] + a[3] * a[3];
    float n2 = a[4] * a[4] + a[5] * a[5] + a[6] * a[6] + a[7] * a[7] + a[8] * a[8];
    float A02 = A0 * A0;
    out0 = ld(Wp0, b0i + 0, isf32) * A0 + ld(Wp0, b0i + 1, isf32) * A02 +
           ld(Wp0, b0i + 2, isf32) * A02 * A0 + ld(Wp0, b0i + 3, isf32) * n1 +
           ld(Wp0, b0i + 4, isf32) * n2 + ld(Wp0, b0i + 5, isf32) * A0 * n1;
    float gp = ld(Wp1, b1i + 0, isf32) + ld(Wp1, b1i + 1, isf32) * A0 +
               ld(Wp1, b1i + 2, isf32) * A02;
    o1x = gp * a[1]; o1y = gp * a[2]; o1z = gp * a[3];
    s0l[f] = out0;
    if (L == 0) { o1l[0][f] = o1x; o1l[1][f] = o1y; o1l[2][f] = o1z; }
  }
  __syncthreads();
  if (t < 64) {
    int f = t;
    if (L == 0) {
      // next-layer node linear into XS1 (read in the next dispatch)
      float b0 = 0.f, bx = 0.f, by = 0.f, bz = 0.f;
      #pragma unroll 8
      for (int q = 0; q < 64; ++q) {
        float w0 = ld(W_lin, 3 * 4096 + q * 64 + f, isf32);  // layer1, path0
        float w1 = ld(W_lin, 4 * 4096 + q * 64 + f, isf32);  // layer1, path1
        b0 += s0l[q] * w0;
        bx += o1l[0][q] * w1; by += o1l[1][q] * w1; bz += o1l[2][q] * w1;
      }
      f32x4 o = {b0, bx, by, bz};
      *(f32x4*)&ws[WS_XS1 + (j * 64 + f) * 4] = o;
    }
    float hacc = ld(br1, L * 64 + f, isf32);
    #pragma unroll 8
    for (int q = 0; q < 64; ++q)
      hacc += s0l[q] * ld(Wr1, (L * 64 + q) * 64 + f, isf32);
    hl[f] = hacc / (1.f + __expf(-hacc));
  }
  __syncthreads();
  if (t < 64) {
    int f = t;
    float gacc = 0.f;
    #pragma unroll 8
    for (int m = 0; m < 64; ++m)
      gacc += hl[m] * ld(Wr2g, (L * 64 + m) * 64 + f, isf32);
    float px = gacc * o1x, py = gacc * o1y, pz = gacc * o1z;
    #pragma unroll
    for (int off = 32; off > 0; off >>= 1) {
      px += __shfl_down(px, off);
      py += __shfl_down(py, off);
      pz += __shfl_down(pz, off);
    }
    if (f == 0) {
      if (L == 0) {
        ws[WS_DELTA + j * 3 + 0] = px;
        ws[WS_DELTA + j * 3 + 1] = py;
        ws[WS_DELTA + j * 3 + 2] = pz;
        ws[WS_POS2 + j * 3 + 0] = pos[j * 3 + 0] + px;
        ws[WS_POS2 + j * 3 + 1] = pos[j * 3 + 1] + py;
        ws[WS_POS2 + j * 3 + 2] = pos[j * 3 + 2] + pz;
      } else {
        float ox = ws[WS_DELTA + j * 3 + 0] + px;
        float oy = ws[WS_DELTA + j * 3 + 1] + py;
        float oz = ws[WS_DELTA + j * 3 + 2] + pz;
        if (isf32) {
          float* o = (float*)out;
          o[j * 3 + 0] = ox; o[j * 3 + 1] = oy; o[j * 3 + 2] = oz;
        } else {
          bf16* o = (bf16*)out;
          o[j * 3 + 0] = __float2bfloat16(ox);
          o[j * 3 + 1] = __float2bfloat16(oy);
          o[j * 3 + 2] = __float2bfloat16(oz);
        }
      }
    }
  }
}

extern "C" void kernel_launch(void* const* d_in, const int* in_sizes, int n_in,
                              void* d_out, int out_size, void* d_ws, size_t ws_size,
                              hipStream_t stream) {
  const void* positions = d_in[0];
  const int*  nodef     = (const int*)d_in[1];
  const void* te        = d_in[2];
  const void* W_embed   = d_in[5];
  const void* b_embed   = d_in[6];
  const void* W_lin     = d_in[7];
  const void* W_e1      = d_in[8];
  const void* b_e1      = d_in[9];
  const void* W_e2      = d_in[10];
  const void* Wp0       = d_in[11];
  const void* Wp1       = d_in[12];
  const void* Wr1       = d_in[13];
  const void* br1       = d_in[14];
  const void* Wr2g      = d_in[16];
  float* ws = (float*)d_ws;
  (void)in_sizes; (void)n_in; (void)out_size; (void)ws_size;

  k_pre<<<dim3(6), dim3(256), 0, stream>>>(positions, te, W_embed, b_embed,
                                           W_lin, ws);
  k_edgenode<0><<<dim3(512), dim3(256), 0, stream>>>(
      nodef, W_lin, W_e1, b_e1, W_e2, Wp0, Wp1, Wr1, br1, Wr2g, ws, d_out);
  k_edgenode<1><<<dim3(512), dim3(256), 0, stream>>>(
      nodef, W_lin, W_e1, b_e1, W_e2, Wp0, Wp1, Wr1, br1, Wr2g, ws, d_out);
}